// Round 9
// baseline (229.904 us; speedup 1.0000x reference)
//
#include <hip/hip_runtime.h>
#include <hip/hip_bf16.h>

#define D 128
#define CAP 64      // max in-degree slots per node (Poisson(12); P(>=64) ~ 1e-24)
#define BM 64
#define CSTR 32     // cnt stride in ints: 1 counter per 128B line (no false sharing)

using bf16x8 = __attribute__((ext_vector_type(8))) short;
using f32x4  = __attribute__((ext_vector_type(4))) float;

static __device__ __forceinline__ unsigned short f2bf(float f) {
    unsigned u = __float_as_uint(f);
    u += 0x7FFF + ((u >> 16) & 1);          // round-to-nearest-even
    return (unsigned short)(u >> 16);
}
static __device__ __forceinline__ float bf2f(unsigned short s) {
    return __uint_as_float(((unsigned)s) << 16);
}

// ---------------------------------------------------------------------------
// Fused prep: convert graph_x fp32->bf16 ; build Wt[h][n][k] ; zero padded cnt.
// ---------------------------------------------------------------------------
__global__ __launch_bounds__(256) void prep_fused(
    const float* __restrict__ xin, ushort* __restrict__ xb,
    const float* __restrict__ Ws, const float* __restrict__ Wn,
    ushort* __restrict__ Wt, int* __restrict__ cnt,
    long n8, int wtot, int nzero4, int nConv, int nWt)
{
    const int b = blockIdx.x;
    if (b < nConv) {
        long i = (long)b * 256 + threadIdx.x;
        if (i >= n8) return;
        const float4* p = (const float4*)xin + i * 2;
        float4 a = p[0], v = p[1];
        uint4 o;
        o.x = (unsigned)f2bf(a.x) | ((unsigned)f2bf(a.y) << 16);
        o.y = (unsigned)f2bf(a.z) | ((unsigned)f2bf(a.w) << 16);
        o.z = (unsigned)f2bf(v.x) | ((unsigned)f2bf(v.y) << 16);
        o.w = (unsigned)f2bf(v.z) | ((unsigned)f2bf(v.w) << 16);
        ((uint4*)xb)[i] = o;
    } else if (b < nConv + nWt) {
        int idx = (b - nConv) * 256 + threadIdx.x;
        if (idx >= wtot) return;
        int h   = idx >> 15;          // /(D*256)
        int rem = idx & 32767;
        int n   = rem >> 8;
        int k   = rem & 255;
        float v = (k < D) ? Ws[(size_t)h * D * D + (size_t)k * D + n]
                          : Wn[(size_t)h * D * D + (size_t)(k - D) * D + n];
        Wt[idx] = f2bf(v);
    } else {
        int idx = (b - nConv - nWt) * 256 + threadIdx.x;
        if (idx >= nzero4) return;
        int4 z = {0, 0, 0, 0};
        ((int4*)cnt)[idx] = z;
    }
}

// ---------------------------------------------------------------------------
// Padded adjacency: one returning atomic (private 128B line) + one 8B scatter.
// ---------------------------------------------------------------------------
__global__ __launch_bounds__(256) void fill_edges(
    const int* __restrict__ ei, const float* __restrict__ w,
    int* __restrict__ cnt, int2* __restrict__ pad, int E)
{
    int e = blockIdx.x * 256 + threadIdx.x;
    if (e >= E) return;
    int s = ei[e];
    int d = ei[E + e];
    float wv = w[e];
    int pos = atomicAdd(&cnt[(size_t)d * CSTR], 1);
    if (pos < CAP) {
        pad[(size_t)d * CAP + pos] = make_int2(s, __float_as_int(wv));
    }
}

// ---------------------------------------------------------------------------
// Fused aggregate + MFMA GEMM: xout = relu([xin | agg(xin)] @ Wt^T + bias).
// Phase A: each wave aggregates its own 16 rows into Agg LDS (wave-private:
//          wave w writes/reads only rows w*16..w*16+15 -> no barrier needed).
// Phase B: K=256 MFMA loop; kc=0,1 A-frags from staged xin (As), kc=2,3 from
//          Agg. NOTE: xout MUST NOT alias xin (Phase A gathers arbitrary
//          rows of xin) -> caller ping-pongs buffers.
// ---------------------------------------------------------------------------
__global__ __launch_bounds__(256) void gemm_agg(
    const ushort* __restrict__ xin, const int* __restrict__ cnt,
    const int2* __restrict__ pad, const ushort* __restrict__ Wt,
    const float* __restrict__ bias, ushort* __restrict__ xout, int nrows)
{
    __shared__ ushort As[BM][72];
    __shared__ ushort Bs[D][72];
    __shared__ ushort Agg[BM][136];
    const int tid  = threadIdx.x;
    const int w    = tid >> 6;
    const int lane = tid & 63;
    const int r16  = lane & 15;
    const int kq   = lane >> 4;
    const int row0 = blockIdx.x * BM;

    // ---- Phase A: aggregate 16 nodes per wave into Agg ----
    {
        const int c  = lane & 31;
        const int jj = lane >> 5;
        for (int i = 0; i < 16; ++i) {
            const int r = w * 16 + i;
            const int n = row0 + r;
            if (n >= nrows) {
                if (jj == 0) {
                    ushort4 z = {0, 0, 0, 0};
                    *((ushort4*)&Agg[r][0] + c) = z;
                }
                continue;
            }
            int deg = cnt[(size_t)n * CSTR];
            if (deg > CAP) deg = CAP;
            const size_t base = (size_t)n * CAP;

            float ax = 0.f, ay = 0.f, az = 0.f, aw = 0.f, wsum = 0.f;
            for (int t = 0; t < deg; t += 8) {
                const int j = t + jj * 4;
                int4 p01 = *(const int4*)(pad + base + j);
                int4 p23 = *(const int4*)(pad + base + j + 2);
                const int s0 = (j + 0 < deg) ? p01.x : 0;
                const int s1 = (j + 1 < deg) ? p01.z : 0;
                const int s2 = (j + 2 < deg) ? p23.x : 0;
                const int s3 = (j + 3 < deg) ? p23.z : 0;
                const float w0 = (j + 0 < deg) ? __int_as_float(p01.y) : 0.f;
                const float w1 = (j + 1 < deg) ? __int_as_float(p01.w) : 0.f;
                const float w2 = (j + 2 < deg) ? __int_as_float(p23.y) : 0.f;
                const float w3 = (j + 3 < deg) ? __int_as_float(p23.w) : 0.f;
                ushort4 v0 = *((const ushort4*)(xin + (size_t)s0 * D) + c);
                ushort4 v1 = *((const ushort4*)(xin + (size_t)s1 * D) + c);
                ushort4 v2 = *((const ushort4*)(xin + (size_t)s2 * D) + c);
                ushort4 v3 = *((const ushort4*)(xin + (size_t)s3 * D) + c);
                ax += w0 * bf2f(v0.x) + w1 * bf2f(v1.x) + w2 * bf2f(v2.x) + w3 * bf2f(v3.x);
                ay += w0 * bf2f(v0.y) + w1 * bf2f(v1.y) + w2 * bf2f(v2.y) + w3 * bf2f(v3.y);
                az += w0 * bf2f(v0.z) + w1 * bf2f(v1.z) + w2 * bf2f(v2.z) + w3 * bf2f(v3.z);
                aw += w0 * bf2f(v0.w) + w1 * bf2f(v1.w) + w2 * bf2f(v2.w) + w3 * bf2f(v3.w);
                wsum += w0 + w1 + w2 + w3;
            }
            ax += __shfl_xor(ax, 32, 64);
            ay += __shfl_xor(ay, 32, 64);
            az += __shfl_xor(az, 32, 64);
            aw += __shfl_xor(aw, 32, 64);
            wsum += __shfl_xor(wsum, 32, 64);
            if (jj == 0) {
                const float inv = 1.f / fmaxf(wsum, 1e-12f);
                ushort4 o;
                o.x = f2bf(ax * inv); o.y = f2bf(ay * inv);
                o.z = f2bf(az * inv); o.w = f2bf(aw * inv);
                *((ushort4*)&Agg[r][0] + c) = o;
            }
        }
    }

    // ---- Phase B: MFMA over K=256 ----
    f32x4 acc[8];
    #pragma unroll
    for (int nf = 0; nf < 8; ++nf) acc[nf] = {0.f, 0.f, 0.f, 0.f};

    for (int kc = 0; kc < 4; ++kc) {
        if (kc < 2) {   // stage xin chunk into As
            const int kb = kc * 64;
            const int r = tid >> 2, q = tid & 3;
            const int grow = row0 + r;
            if (grow < nrows) {
                const uint4* gp = (const uint4*)(xin + (size_t)grow * D + kb + q * 16);
                uint4 v0 = gp[0], v1 = gp[1];
                *(uint4*)&As[r][q * 16]     = v0;
                *(uint4*)&As[r][q * 16 + 8] = v1;
            } else {
                uint4 z = {0u, 0u, 0u, 0u};
                *(uint4*)&As[r][q * 16]     = z;
                *(uint4*)&As[r][q * 16 + 8] = z;
            }
        }
        {   // stage B chunk (Wt rows)
            const int n = tid >> 1, h2 = tid & 1;
            const uint4* gp = (const uint4*)(Wt + (size_t)n * 256 + kc * 64 + h2 * 32);
            uint4 v0 = gp[0], v1 = gp[1], v2 = gp[2], v3 = gp[3];
            *(uint4*)&Bs[n][h2 * 32]      = v0;
            *(uint4*)&Bs[n][h2 * 32 + 8]  = v1;
            *(uint4*)&Bs[n][h2 * 32 + 16] = v2;
            *(uint4*)&Bs[n][h2 * 32 + 24] = v3;
        }
        __syncthreads();
        #pragma unroll
        for (int kk = 0; kk < 64; kk += 32) {
            bf16x8 a;
            if (kc < 2)
                a = *(const bf16x8*)&As[w * 16 + r16][kk + kq * 8];
            else
                a = *(const bf16x8*)&Agg[w * 16 + r16][(kc - 2) * 64 + kk + kq * 8];
            #pragma unroll
            for (int nf = 0; nf < 8; ++nf) {
                bf16x8 b = *(const bf16x8*)&Bs[nf * 16 + r16][kk + kq * 8];
                acc[nf] = __builtin_amdgcn_mfma_f32_16x16x32_bf16(a, b, acc[nf], 0, 0, 0);
            }
        }
        __syncthreads();
    }
    // epilogue: bias + relu + bf16 store
    #pragma unroll
    for (int nf = 0; nf < 8; ++nf) {
        const int col = nf * 16 + r16;
        const float bv = bias[col];
        #pragma unroll
        for (int i = 0; i < 4; ++i) {
            const int grow = row0 + w * 16 + kq * 4 + i;
            if (grow < nrows) {
                float v = fmaxf(acc[nf][i] + bv, 0.f);
                xout[(size_t)grow * D + col] = f2bf(v);
            }
        }
    }
}

// ---------------------------------------------------------------------------
// out[q] = fp32(x2b[x_nodes[q]]) + effect_emb[effect_ids[q]]
// ---------------------------------------------------------------------------
__global__ __launch_bounds__(256) void out_kernel(
    const ushort* __restrict__ x, const float* __restrict__ emb,
    const int* __restrict__ xn, const int* __restrict__ eid,
    float* __restrict__ out, int Q)
{
    long g = (long)blockIdx.x * 256 + threadIdx.x;
    long tot = (long)Q * 32;
    if (g >= tot) return;
    int q = (int)(g >> 5);
    int c = (int)(g & 31);
    int nq = xn[q], ef = eid[q];
    ushort4 xv = *((const ushort4*)(x + (size_t)nq * D) + c);
    float4  ev = *((const float4*)(emb + (size_t)ef * D) + c);
    float4 o = {bf2f(xv.x) + ev.x, bf2f(xv.y) + ev.y,
                bf2f(xv.z) + ev.z, bf2f(xv.w) + ev.w};
    ((float4*)out)[g] = o;
}

extern "C" void kernel_launch(void* const* d_in, const int* in_sizes, int n_in,
                              void* d_out, int out_size, void* d_ws, size_t ws_size,
                              hipStream_t stream)
{
    const float* graph_x   = (const float*)d_in[0];
    const int*   edge_idx  = (const int*)d_in[1];
    const int*   x_nodes   = (const int*)d_in[2];
    const int*   effect_id = (const int*)d_in[3];
    const float* chem      = (const float*)d_in[4];
    const float* W_self    = (const float*)d_in[5];
    const float* W_neigh   = (const float*)d_in[6];
    const float* bias      = (const float*)d_in[7];
    const float* eff_emb   = (const float*)d_in[8];

    const int N    = in_sizes[0] / D;
    const int E    = in_sizes[4];
    const int Q    = in_sizes[2];
    const int HOPS = in_sizes[7] / D;

    char* wsp = (char*)d_ws;
    int*    cnt  = (int*)wsp;     wsp += (size_t)N * CSTR * 4;   // 1 counter / 128B
    int2*   pad  = (int2*)wsp;    wsp += (size_t)N * CAP * 8;
    ushort* xb   = (ushort*)wsp;  wsp += (size_t)N * D * 2;
    ushort* x1b  = (ushort*)wsp;  wsp += (size_t)N * D * 2;
    ushort* x2b  = (ushort*)wsp;  wsp += (size_t)N * D * 2;
    ushort* Wt   = (ushort*)wsp;  wsp += (size_t)HOPS * D * 256 * 2;

    // fused prep: convert_x + prep_wt + zero padded cnt
    const long n8     = (long)N * D / 8;
    const int  wtot   = HOPS * D * 256;
    const int  nzero4 = N * CSTR / 4;
    const int  nConv  = (int)((n8 + 255) / 256);
    const int  nWt    = (wtot + 255) / 256;
    const int  nZero  = (nzero4 + 255) / 256;
    prep_fused<<<nConv + nWt + nZero, 256, 0, stream>>>(
        graph_x, xb, W_self, W_neigh, Wt, cnt, n8, wtot, nzero4, nConv, nWt);

    fill_edges<<<(E + 255) / 256, 256, 0, stream>>>(
        edge_idx, chem, cnt, pad, E);

    // ping-pong buffers: Phase A gathers arbitrary rows of xin, so xout
    // must never alias xin (R8 race).
    ushort* bufs[3] = {xb, x1b, x2b};
    const int gemmGrid = (N + BM - 1) / BM;
    for (int h = 0; h < HOPS; ++h) {
        const ushort* xin = bufs[h];
        ushort* xout      = bufs[h + 1 == 3 ? 1 : h + 1];   // xb -> x1b -> x2b -> x1b...
        gemm_agg<<<gemmGrid, 256, 0, stream>>>(
            xin, cnt, pad, Wt + (size_t)h * D * 256, bias + (size_t)h * D, xout, N);
    }
    const ushort* xfin = bufs[HOPS == 1 ? 1 : (HOPS % 2 == 0 ? 2 : 1)];

    long tot = (long)Q * 32;
    out_kernel<<<(int)((tot + 255) / 256), 256, 0, stream>>>(
        xfin, eff_emb, x_nodes, effect_id, (float*)d_out, Q);
}

// Round 10
// 143.436 us; speedup vs baseline: 1.6028x; 1.6028x over previous
//
#include <hip/hip_runtime.h>
#include <hip/hip_bf16.h>

#define D 128
#define CAP 64      // max in-degree slots per node (Poisson(12); P(>=64) ~ 1e-24)
#define BM 64
#define CSTR 32     // cnt stride in ints: 1 counter per 128B line (no false sharing)

using bf16x8 = __attribute__((ext_vector_type(8))) short;
using f32x4  = __attribute__((ext_vector_type(4))) float;

static __device__ __forceinline__ unsigned short f2bf(float f) {
    unsigned u = __float_as_uint(f);
    u += 0x7FFF + ((u >> 16) & 1);          // round-to-nearest-even
    return (unsigned short)(u >> 16);
}
static __device__ __forceinline__ float bf2f(unsigned short s) {
    return __uint_as_float(((unsigned)s) << 16);
}
static __device__ __forceinline__ void acc8(float* a, uint4 v, float w) {
    a[0] += w * bf2f((ushort)(v.x & 0xffff));
    a[1] += w * bf2f((ushort)(v.x >> 16));
    a[2] += w * bf2f((ushort)(v.y & 0xffff));
    a[3] += w * bf2f((ushort)(v.y >> 16));
    a[4] += w * bf2f((ushort)(v.z & 0xffff));
    a[5] += w * bf2f((ushort)(v.z >> 16));
    a[6] += w * bf2f((ushort)(v.w & 0xffff));
    a[7] += w * bf2f((ushort)(v.w >> 16));
}

// ---------------------------------------------------------------------------
// Fused prep: convert graph_x fp32->bf16 ; build Wt[h][n][k] ; zero padded cnt.
// ---------------------------------------------------------------------------
__global__ __launch_bounds__(256) void prep_fused(
    const float* __restrict__ xin, ushort* __restrict__ xb,
    const float* __restrict__ Ws, const float* __restrict__ Wn,
    ushort* __restrict__ Wt, int* __restrict__ cnt,
    long n8, int wtot, int nzero4, int nConv, int nWt)
{
    const int b = blockIdx.x;
    if (b < nConv) {
        long i = (long)b * 256 + threadIdx.x;
        if (i >= n8) return;
        const float4* p = (const float4*)xin + i * 2;
        float4 a = p[0], v = p[1];
        uint4 o;
        o.x = (unsigned)f2bf(a.x) | ((unsigned)f2bf(a.y) << 16);
        o.y = (unsigned)f2bf(a.z) | ((unsigned)f2bf(a.w) << 16);
        o.z = (unsigned)f2bf(v.x) | ((unsigned)f2bf(v.y) << 16);
        o.w = (unsigned)f2bf(v.z) | ((unsigned)f2bf(v.w) << 16);
        ((uint4*)xb)[i] = o;
    } else if (b < nConv + nWt) {
        int idx = (b - nConv) * 256 + threadIdx.x;
        if (idx >= wtot) return;
        int h   = idx >> 15;          // /(D*256)
        int rem = idx & 32767;
        int n   = rem >> 8;
        int k   = rem & 255;
        float v = (k < D) ? Ws[(size_t)h * D * D + (size_t)k * D + n]
                          : Wn[(size_t)h * D * D + (size_t)(k - D) * D + n];
        Wt[idx] = f2bf(v);
    } else {
        int idx = (b - nConv - nWt) * 256 + threadIdx.x;
        if (idx >= nzero4) return;
        int4 z = {0, 0, 0, 0};
        ((int4*)cnt)[idx] = z;
    }
}

// ---------------------------------------------------------------------------
// Padded adjacency: one returning atomic (private 128B line) + one 8B scatter.
// ---------------------------------------------------------------------------
__global__ __launch_bounds__(256) void fill_edges(
    const int* __restrict__ ei, const float* __restrict__ w,
    int* __restrict__ cnt, int2* __restrict__ pad, int E)
{
    int e = blockIdx.x * 256 + threadIdx.x;
    if (e >= E) return;
    int s = ei[e];
    int d = ei[E + e];
    float wv = w[e];
    int pos = atomicAdd(&cnt[(size_t)d * CSTR], 1);
    if (pos < CAP) {
        pad[(size_t)d * CAP + pos] = make_int2(s, __float_as_int(wv));
    }
}

// ---------------------------------------------------------------------------
// Weighted-mean aggregation, one node per wave, 16 slots in flight:
//   c  = lane & 15 : 8-column group (16 x 8 = 128 cols, ushort8 loads)
//   jj = lane >> 4 : 4 j-slices x 4 slots each
// deg <= 16 (~90% of nodes) needs ONE dependent slot->gather step (was 2).
// Cross-slice reduce: shfl_xor 16 then 32. Poison slots predicated to (0,0).
// ---------------------------------------------------------------------------
__global__ __launch_bounds__(256) void aggregate(
    const ushort* __restrict__ x, const int* __restrict__ cnt,
    const int2* __restrict__ pad, ushort* __restrict__ agg, int N)
{
    const int wave = threadIdx.x >> 6;
    const int lane = threadIdx.x & 63;
    const int n = blockIdx.x * 4 + wave;
    if (n >= N) return;
    const int c  = lane & 15;
    const int jj = lane >> 4;

    int deg = cnt[(size_t)n * CSTR];
    if (deg > CAP) deg = CAP;
    const size_t base = (size_t)n * CAP;

    float a[8] = {0.f, 0.f, 0.f, 0.f, 0.f, 0.f, 0.f, 0.f};
    float wsum = 0.f;

    for (int t = 0; t < deg; t += 16) {
        const int j = t + jj * 4;          // j+3 <= 48+15 = 63 : in-bounds
        int4 p01 = *(const int4*)(pad + base + j);
        int4 p23 = *(const int4*)(pad + base + j + 2);
        const int s0 = (j + 0 < deg) ? p01.x : 0;
        const int s1 = (j + 1 < deg) ? p01.z : 0;
        const int s2 = (j + 2 < deg) ? p23.x : 0;
        const int s3 = (j + 3 < deg) ? p23.z : 0;
        const float w0 = (j + 0 < deg) ? __int_as_float(p01.y) : 0.f;
        const float w1 = (j + 1 < deg) ? __int_as_float(p01.w) : 0.f;
        const float w2 = (j + 2 < deg) ? __int_as_float(p23.y) : 0.f;
        const float w3 = (j + 3 < deg) ? __int_as_float(p23.w) : 0.f;
        uint4 v0 = *(const uint4*)(x + (size_t)s0 * D + c * 8);
        uint4 v1 = *(const uint4*)(x + (size_t)s1 * D + c * 8);
        uint4 v2 = *(const uint4*)(x + (size_t)s2 * D + c * 8);
        uint4 v3 = *(const uint4*)(x + (size_t)s3 * D + c * 8);
        acc8(a, v0, w0);
        acc8(a, v1, w1);
        acc8(a, v2, w2);
        acc8(a, v3, w3);
        wsum += w0 + w1 + w2 + w3;
    }

    #pragma unroll
    for (int i = 0; i < 8; ++i) {
        a[i] += __shfl_xor(a[i], 16, 64);
        a[i] += __shfl_xor(a[i], 32, 64);
    }
    wsum += __shfl_xor(wsum, 16, 64);
    wsum += __shfl_xor(wsum, 32, 64);

    if (jj == 0) {
        const float inv = 1.f / fmaxf(wsum, 1e-12f);
        uint4 o;
        o.x = (unsigned)f2bf(a[0] * inv) | ((unsigned)f2bf(a[1] * inv) << 16);
        o.y = (unsigned)f2bf(a[2] * inv) | ((unsigned)f2bf(a[3] * inv) << 16);
        o.z = (unsigned)f2bf(a[4] * inv) | ((unsigned)f2bf(a[5] * inv) << 16);
        o.w = (unsigned)f2bf(a[6] * inv) | ((unsigned)f2bf(a[7] * inv) << 16);
        *(uint4*)(agg + (size_t)n * D + c * 8) = o;
    }
}

// ---------------------------------------------------------------------------
// MFMA GEMM: xout = relu([xin|agg] @ Wt^T + bias), all bf16 I/O, fp32 acc.
// In-place (xout==xin) safe: each block reads only its own xin rows.
// ---------------------------------------------------------------------------
__global__ __launch_bounds__(256) void gemm_mfma(
    const ushort* __restrict__ xin, const ushort* __restrict__ agg,
    const ushort* __restrict__ Wt, const float* __restrict__ bias,
    ushort* __restrict__ xout, int nrows)
{
    __shared__ ushort As[BM][72];
    __shared__ ushort Bs[D][72];
    const int tid  = threadIdx.x;
    const int w    = tid >> 6;
    const int lane = tid & 63;
    const int r16  = lane & 15;
    const int kq   = lane >> 4;
    const int row0 = blockIdx.x * BM;

    f32x4 acc[8];
    #pragma unroll
    for (int nf = 0; nf < 8; ++nf) acc[nf] = {0.f, 0.f, 0.f, 0.f};

    for (int kc = 0; kc < 4; ++kc) {
        {
            const ushort* src = (kc < 2) ? xin : agg;
            const int kb = (kc & 1) * 64;
            const int r = tid >> 2, q = tid & 3;
            const int grow = row0 + r;
            if (grow < nrows) {
                const uint4* gp = (const uint4*)(src + (size_t)grow * D + kb + q * 16);
                uint4 v0 = gp[0], v1 = gp[1];
                *(uint4*)&As[r][q * 16]     = v0;
                *(uint4*)&As[r][q * 16 + 8] = v1;
            } else {
                uint4 z = {0u, 0u, 0u, 0u};
                *(uint4*)&As[r][q * 16]     = z;
                *(uint4*)&As[r][q * 16 + 8] = z;
            }
        }
        {
            const int n = tid >> 1, h2 = tid & 1;
            const uint4* gp = (const uint4*)(Wt + (size_t)n * 256 + kc * 64 + h2 * 32);
            uint4 v0 = gp[0], v1 = gp[1], v2 = gp[2], v3 = gp[3];
            *(uint4*)&Bs[n][h2 * 32]      = v0;
            *(uint4*)&Bs[n][h2 * 32 + 8]  = v1;
            *(uint4*)&Bs[n][h2 * 32 + 16] = v2;
            *(uint4*)&Bs[n][h2 * 32 + 24] = v3;
        }
        __syncthreads();
        #pragma unroll
        for (int kk = 0; kk < 64; kk += 32) {
            bf16x8 a = *(const bf16x8*)&As[w * 16 + r16][kk + kq * 8];
            #pragma unroll
            for (int nf = 0; nf < 8; ++nf) {
                bf16x8 b = *(const bf16x8*)&Bs[nf * 16 + r16][kk + kq * 8];
                acc[nf] = __builtin_amdgcn_mfma_f32_16x16x32_bf16(a, b, acc[nf], 0, 0, 0);
            }
        }
        __syncthreads();
    }
    #pragma unroll
    for (int nf = 0; nf < 8; ++nf) {
        const int col = nf * 16 + r16;
        const float bv = bias[col];
        #pragma unroll
        for (int i = 0; i < 4; ++i) {
            const int grow = row0 + w * 16 + kq * 4 + i;
            if (grow < nrows) {
                float v = fmaxf(acc[nf][i] + bv, 0.f);
                xout[(size_t)grow * D + col] = f2bf(v);
            }
        }
    }
}

// ---------------------------------------------------------------------------
// out[q] = fp32(x2b[x_nodes[q]]) + effect_emb[effect_ids[q]]
// ---------------------------------------------------------------------------
__global__ __launch_bounds__(256) void out_kernel(
    const ushort* __restrict__ x, const float* __restrict__ emb,
    const int* __restrict__ xn, const int* __restrict__ eid,
    float* __restrict__ out, int Q)
{
    long g = (long)blockIdx.x * 256 + threadIdx.x;
    long tot = (long)Q * 32;
    if (g >= tot) return;
    int q = (int)(g >> 5);
    int c = (int)(g & 31);
    int nq = xn[q], ef = eid[q];
    ushort4 xv = *((const ushort4*)(x + (size_t)nq * D) + c);
    float4  ev = *((const float4*)(emb + (size_t)ef * D) + c);
    float4 o = {bf2f(xv.x) + ev.x, bf2f(xv.y) + ev.y,
                bf2f(xv.z) + ev.z, bf2f(xv.w) + ev.w};
    ((float4*)out)[g] = o;
}

extern "C" void kernel_launch(void* const* d_in, const int* in_sizes, int n_in,
                              void* d_out, int out_size, void* d_ws, size_t ws_size,
                              hipStream_t stream)
{
    const float* graph_x   = (const float*)d_in[0];
    const int*   edge_idx  = (const int*)d_in[1];
    const int*   x_nodes   = (const int*)d_in[2];
    const int*   effect_id = (const int*)d_in[3];
    const float* chem      = (const float*)d_in[4];
    const float* W_self    = (const float*)d_in[5];
    const float* W_neigh   = (const float*)d_in[6];
    const float* bias      = (const float*)d_in[7];
    const float* eff_emb   = (const float*)d_in[8];

    const int N    = in_sizes[0] / D;
    const int E    = in_sizes[4];
    const int Q    = in_sizes[2];
    const int HOPS = in_sizes[7] / D;

    char* wsp = (char*)d_ws;
    int*    cnt  = (int*)wsp;     wsp += (size_t)N * CSTR * 4;   // 1 counter / 128B
    int2*   pad  = (int2*)wsp;    wsp += (size_t)N * CAP * 8;
    ushort* xb   = (ushort*)wsp;  wsp += (size_t)N * D * 2;
    ushort* aggb = (ushort*)wsp;  wsp += (size_t)N * D * 2;
    ushort* x1b  = (ushort*)wsp;  wsp += (size_t)N * D * 2;
    ushort* Wt   = (ushort*)wsp;  wsp += (size_t)HOPS * D * 256 * 2;

    // fused prep: convert_x + prep_wt + zero padded cnt
    const long n8     = (long)N * D / 8;
    const int  wtot   = HOPS * D * 256;
    const int  nzero4 = N * CSTR / 4;
    const int  nConv  = (int)((n8 + 255) / 256);
    const int  nWt    = (wtot + 255) / 256;
    const int  nZero  = (nzero4 + 255) / 256;
    prep_fused<<<nConv + nWt + nZero, 256, 0, stream>>>(
        graph_x, xb, W_self, W_neigh, Wt, cnt, n8, wtot, nzero4, nConv, nWt);

    fill_edges<<<(E + 255) / 256, 256, 0, stream>>>(
        edge_idx, chem, cnt, pad, E);

    const int aggGrid  = (N + 3) / 4;
    const int gemmGrid = (N + BM - 1) / BM;

    for (int h = 0; h < HOPS; ++h) {
        const ushort* xin = (h == 0) ? xb : x1b;
        aggregate<<<aggGrid, 256, 0, stream>>>(xin, cnt, pad, aggb, N);
        gemm_mfma<<<gemmGrid, 256, 0, stream>>>(
            xin, aggb, Wt + (size_t)h * D * 256, bias + (size_t)h * D, x1b, N);
    }

    long tot = (long)Q * 32;
    out_kernel<<<(int)((tot + 255) / 256), 256, 0, stream>>>(
        x1b, eff_emb, x_nodes, effect_id, (float*)d_out, Q);
}